// Round 6
// baseline (139.751 us; speedup 1.0000x reference)
//
#include <hip/hip_runtime.h>
#include <hip/hip_bf16.h>

// ---------------------------------------------------------------------------
// EuclideanDeconf: out[b,c] = (2*dot(x[b],W[c]) - ||x[b]||^2 - ||W[c]||^2) / D
// R12: occupancy fix. R10 (2-phase) == R11 (1-phase PD=2 ring) == ~135.5us
// proved the gemm is NOT schedule-bound but CU-idle-bound: 256 blocks = 1
// block/CU, 8 lockstep waves -> every sync idles the CU. R12 keeps R11's
// pipeline (MX MFMA, DMA staging w/ pre-swizzled source, 3-buf ring, PD=2
// flight, counted vmcnt, setprio) at TM=TN=128 / 256 thr (4 waves 2x2) /
// 48 KB LDS -> 3 blocks/CU co-resident (grid 32x8x4=1024). Desynced blocks
// fill each other's barrier stalls (R8 proved 3/CU => 42% of MFMA floor).
// fp8 partials (1/16), split-K=4 unchanged.
// ---------------------------------------------------------------------------

typedef float f32x4 __attribute__((ext_vector_type(4)));
typedef float f32x2 __attribute__((ext_vector_type(2)));
typedef float f32x16 __attribute__((ext_vector_type(16)));
typedef int i32x4 __attribute__((ext_vector_type(4)));
typedef int i32x8 __attribute__((ext_vector_type(8)));

#define BDIM 4096
#define DDIM 4096
#define CDIM 1024
#define TM 128
#define TN 128
#define BK 64
#define KSPLIT 4
#define NIT ((DDIM / KSPLIT) / BK)   // 16
#define SCALE 32.0f
#define INV_SS (1.0f/1024.0f)
#define PSCALE 0.0625f               // partial pack scale (1/16)

#define WAITV(N) asm volatile("s_waitcnt vmcnt(" #N ")" ::: "memory")

// One WAVE per row: fp32 row -> fp8(e4m3, x SCALE) row + fp32 sum-of-squares
// (of the UNSCALED values).
__global__ __launch_bounds__(256) void cvt_rowsq(
    const float* __restrict__ x, const float* __restrict__ W,
    unsigned char* __restrict__ xb, unsigned char* __restrict__ wb,
    float* __restrict__ xsq, float* __restrict__ wsq)
{
    const int lane = threadIdx.x & 63;
    const int row = blockIdx.x * 4 + (threadIdx.x >> 6);

    const float* src;
    unsigned char* dst;
    float* sq;
    if (row < BDIM) {
        src = x + (size_t)row * DDIM;
        dst = xb + (size_t)row * DDIM;
        sq = xsq + row;
    } else {
        int r = row - BDIM;
        src = W + (size_t)r * DDIM;
        dst = wb + (size_t)r * DDIM;
        sq = wsq + r;
    }

    const float4* s4 = (const float4*)src;
    unsigned int* d4 = (unsigned int*)dst;
    float a = 0.f;
    #pragma unroll
    for (int s = 0; s < DDIM / 4 / 64; ++s) {
        float4 f = s4[lane + 64 * s];
        a += f.x * f.x + f.y * f.y + f.z * f.z + f.w * f.w;
        unsigned int p = 0;
        p = __builtin_amdgcn_cvt_pk_fp8_f32(f.x * SCALE, f.y * SCALE, p, false);
        p = __builtin_amdgcn_cvt_pk_fp8_f32(f.z * SCALE, f.w * SCALE, p, true);
        d4[lane + 64 * s] = p;
    }
    #pragma unroll
    for (int off = 32; off > 0; off >>= 1) a += __shfl_down(a, off);
    if (lane == 0) *sq = a;
}

// --- GEMM ---
// LDS: 3 bufs, buf q at q*16384: A[128][64] fp8 at +0, B[128][64] at +8192.
// Swizzle: 16B chunk (row m, chunk c) stored at slot (m, c ^ ((m>>1)&3)).
// Staging: DMA writes linearly (base + lane*16); per-lane SOURCE chunk
// pre-swizzled: lane l loads global chunk (l&3) ^ ((l>>3)&3) of row
// w*32+(l>>2) (+16 for the second inst). Same algebra as R11 (verified:
// wave-uniform row terms are ==0 mod 4, so the lane-local swizzle is exact).
// Frag reads: lane l: row base+(l&31), chunks c0=(l>>5)*2 and c0^1 swizzled
// -> two ds_read_b128; 8-lane groups cover all 32 banks (conflict-free).

__device__ __forceinline__ i32x8 cat8(i32x4 lo, i32x4 hi) {
    return __builtin_shufflevector(lo, hi, 0, 1, 2, 3, 4, 5, 6, 7);
}

#define MXMFMA(A, Bv, C)                                                  \
    __builtin_amdgcn_mfma_scale_f32_32x32x64_f8f6f4(                      \
        (A), (Bv), (C), 0, 0, 0, 0x7F7F7F7F, 0, 0x7F7F7F7F)

#define GLOAD16(gp, lp)                                                   \
    __builtin_amdgcn_global_load_lds(                                     \
        (const __attribute__((address_space(1))) void*)(gp),              \
        (__attribute__((address_space(3))) void*)(lp), 16, 0, 0)

__global__ __launch_bounds__(256, 3) void gemm_eucl(
    const unsigned char* __restrict__ xb,   // [B, D] fp8
    const unsigned char* __restrict__ wb,   // [C, D] fp8
    unsigned int* __restrict__ part)        // [KSPLIT][256 blk][16 fg][256]
{
    __shared__ unsigned char sm[3 * 16384];

    const int tid = threadIdx.x;
    const int lane = tid & 63;
    const int w = tid >> 6;                 // wave 0..3
    const int wr = w >> 1;                  // 0..1  (M half: 64 rows)
    const int wc = w & 1;                   // 0..1  (N half: 64 rows)
    const int bm = blockIdx.x * TM;
    const int bn = blockIdx.y * TN;
    const int ks = blockIdx.z * (DDIM / KSPLIT);

    // ---- staging: per-lane pre-swizzled global sources (coalesced) ----
    const int srow = w * 32 + (lane >> 2);
    const int schunk = ((lane & 3) ^ ((lane >> 3) & 3)) * 16;
    const unsigned char* gA0 = xb + (size_t)(bm + srow) * DDIM + ks + schunk;
    const unsigned char* gA1 = gA0 + (size_t)16 * DDIM;
    const unsigned char* gB0 = wb + (size_t)(bn + srow) * DDIM + ks + schunk;
    const unsigned char* gB1 = gB0 + (size_t)16 * DDIM;
    // wave-uniform LDS dests (DMA adds lane*16)
    unsigned char* lA0 = sm + w * 2048;
    unsigned char* lA1 = lA0 + 1024;
    unsigned char* lB0 = sm + 8192 + w * 2048;
    unsigned char* lB1 = lB0 + 1024;

#define STAGE(q, t)                                                       \
    do {                                                                  \
        GLOAD16(gA0 + (t) * BK, lA0 + (q) * 16384);                       \
        GLOAD16(gA1 + (t) * BK, lA1 + (q) * 16384);                       \
        GLOAD16(gB0 + (t) * BK, lB0 + (q) * 16384);                       \
        GLOAD16(gB1 + (t) * BK, lB1 + (q) * 16384);                       \
    } while (0)

    // ---- fragment read bases (swizzled) ----
    const int s_rd = ((lane & 31) >> 1) & 3;
    const int c0s = ((lane >> 5) * 2) ^ s_rd;
    const unsigned char* aR0 = sm + (wr * 64 + (lane & 31)) * 64 + c0s * 16;
    const unsigned char* aR1 = sm + (wr * 64 + (lane & 31)) * 64 + (c0s ^ 1) * 16;
    const unsigned char* bR0 = sm + 8192 + (wc * 64 + (lane & 31)) * 64 + c0s * 16;
    const unsigned char* bR1 = sm + 8192 + (wc * 64 + (lane & 31)) * 64 + (c0s ^ 1) * 16;

    f32x16 acc[4] = {};   // [i 0..1][j 0..1] -> acc[i*2+j]

    // ---- prologue: tiles 0,1 staged into bufs 0,1 (8 loads in flight) ----
    STAGE(0, 0);
    STAGE(1, 1);

    #pragma unroll
    for (int t = 0; t < NIT; ++t) {
        const int qo = (t % 3) * 16384;
        // tile-t's 4 loads retired; tile-(t+1)'s 4 stay flying
        if (t + 1 < NIT) WAITV(4);
        else             WAITV(0);
        __builtin_amdgcn_s_barrier();
        // stage tile t+2 into buf (t+2)%3 (= buf (t-1)%3, reads done @ t-1)
        if (t + 2 < NIT) STAGE((t + 2) % 3, t + 2);
        // fragments of tile t
        i32x8 fb0 = cat8(*(const i32x4*)(bR0 + qo), *(const i32x4*)(bR1 + qo));
        i32x8 fb1 = cat8(*(const i32x4*)(bR0 + qo + 2048),
                         *(const i32x4*)(bR1 + qo + 2048));
        i32x8 fa0 = cat8(*(const i32x4*)(aR0 + qo), *(const i32x4*)(aR1 + qo));
        i32x8 fa1 = cat8(*(const i32x4*)(aR0 + qo + 2048),
                         *(const i32x4*)(aR1 + qo + 2048));
        __builtin_amdgcn_s_setprio(1);
        acc[0] = MXMFMA(fa0, fb0, acc[0]);
        acc[1] = MXMFMA(fa0, fb1, acc[1]);
        acc[2] = MXMFMA(fa1, fb0, acc[2]);
        acc[3] = MXMFMA(fa1, fb1, acc[3]);
        __builtin_amdgcn_s_setprio(0);
    }

    // ---- fp8 partials, scale 1/16: 16 uints/thread ----
    const int bb = blockIdx.x * 8 + blockIdx.y;          // 0..255
    unsigned int* p = part + ((size_t)blockIdx.z * 256 + bb) * 4096;
    #pragma unroll
    for (int f = 0; f < 4; ++f)
        #pragma unroll
        for (int g = 0; g < 4; ++g) {
            unsigned int pk = 0;
            pk = __builtin_amdgcn_cvt_pk_fp8_f32(
                acc[f][g * 4 + 0] * PSCALE, acc[f][g * 4 + 1] * PSCALE, pk, false);
            pk = __builtin_amdgcn_cvt_pk_fp8_f32(
                acc[f][g * 4 + 2] * PSCALE, acc[f][g * 4 + 3] * PSCALE, pk, true);
            p[(f * 4 + g) * 256 + tid] = pk;
        }
#undef STAGE
}

// 512 blocks x 256 thr; reduce block = half of one gemm-block (8 fg's).
// 32x32 C/D layout: col = lane&31, row = (reg&3) + 8*(reg>>2) + 4*(lane>>5);
// packed grp g holds regs 4g..4g+3 -> row = r + 8g + 4*(lane>>5).
__global__ __launch_bounds__(256) void reduce_out(
    const unsigned int* __restrict__ part, const float* __restrict__ xsq,
    const float* __restrict__ wsq, float* __restrict__ out)
{
    const int bid = blockIdx.x;           // 0..511
    const int bb = bid >> 1;              // gemm block 0..255 (bx*8 + by)
    const int half = bid & 1;
    const int t = threadIdx.x;
    const int lane = t & 63;
    const int w = t >> 6;                 // gemm wave 0..3
    const int wr = w >> 1, wc = w & 1;
    const int bm = (bb >> 3) * TM, bn = (bb & 7) * TN;
    const size_t sl = (size_t)256 * 4096;        // uints per z-slice
    const float c1 = 2.0f * 16.0f * INV_SS / (float)DDIM;  // 16 = 1/PSCALE
    const float c2 = 1.0f / (float)DDIM;

    #pragma unroll
    for (int ff = 0; ff < 8; ++ff) {
        const int fg = half * 8 + ff;     // 0..15
        const int f = fg >> 2;            // acc index 0..3
        const int g = fg & 3;             // packed group
        size_t o = ((size_t)bb * 16 + fg) * 256 + t;
        f32x2 s01 = {0.f, 0.f}, s23 = {0.f, 0.f};
        #pragma unroll
        for (int z = 0; z < KSPLIT; ++z) {
            unsigned int u = part[o + (size_t)z * sl];
            s01 += __builtin_amdgcn_cvt_pk_f32_fp8(u, false);
            s23 += __builtin_amdgcn_cvt_pk_f32_fp8(u, true);
        }
        const int i = f >> 1, j = f & 1;
        const int gn = bn + wc * 64 + j * 32 + (lane & 31);
        const float wv = wsq[gn];
        const int gm0 = bm + wr * 64 + i * 32 + g * 8 + (lane >> 5) * 4;
        float sv[4] = {s01.x, s01.y, s23.x, s23.y};
        #pragma unroll
        for (int r = 0; r < 4; ++r) {
            out[(size_t)(gm0 + r) * CDIM + gn] = sv[r] * c1 - (xsq[gm0 + r] + wv) * c2;
        }
    }
}

// --- Fallback: naive fp32 (any ws) ---
__global__ void fallback_kernel(const float* __restrict__ x, const float* __restrict__ W,
                                float* __restrict__ out)
{
    int c = blockIdx.x * blockDim.x + threadIdx.x;
    int b = blockIdx.y;
    if (c >= CDIM) return;
    const float* xr = x + (size_t)b * DDIM;
    const float* wr = W + (size_t)c * DDIM;
    float xs = 0.f, ws = 0.f, cr = 0.f;
    for (int d = 0; d < DDIM; ++d) {
        float xv = xr[d], wv = wr[d];
        xs += xv * xv; ws += wv * wv; cr += xv * wv;
    }
    out[(size_t)b * CDIM + c] = (2.0f * cr - xs - ws) / (float)DDIM;
}

extern "C" void kernel_launch(void* const* d_in, const int* in_sizes, int n_in,
                              void* d_out, int out_size, void* d_ws, size_t ws_size,
                              hipStream_t stream) {
    const float* x = (const float*)d_in[0];   // [B, D] fp32
    const float* W = (const float*)d_in[1];   // [C, D] fp32
    float* out = (float*)d_out;               // [B, C] fp32

    size_t need = (size_t)(BDIM + CDIM) * DDIM                 // fp8 inputs 20 MB
                + (size_t)(BDIM + CDIM) * sizeof(float)        // norms
                + (size_t)KSPLIT * BDIM * CDIM;                // fp8 partials 16 MB
    if (ws_size < need) {
        fallback_kernel<<<dim3(CDIM / 256, BDIM), 256, 0, stream>>>(x, W, out);
        return;
    }

    unsigned char* xb = (unsigned char*)d_ws;              // 16 MB
    unsigned char* wb = xb + (size_t)BDIM * DDIM;          // 4 MB
    float* xsq = (float*)(wb + (size_t)CDIM * DDIM);       // 16 KB
    float* wsq = xsq + BDIM;                               // 4 KB
    unsigned int* part = (unsigned int*)(wsq + CDIM);      // 16 MB

    cvt_rowsq<<<(BDIM + CDIM) / 4, 256, 0, stream>>>(x, W, xb, wb, xsq, wsq);
    gemm_eucl<<<dim3(BDIM / TM, CDIM / TN, KSPLIT), 256, 0, stream>>>(xb, wb, part);
    reduce_out<<<512, 256, 0, stream>>>(part, xsq, wsq, out);
}

// Round 7
// 134.687 us; speedup vs baseline: 1.0376x; 1.0376x over previous
//
#include <hip/hip_runtime.h>
#include <hip/hip_bf16.h>

// ---------------------------------------------------------------------------
// EuclideanDeconf: out[b,c] = (2*dot(x[b],W[c]) - ||x[b]||^2 - ||W[c]||^2) / D
// R13: fine-grained phase interleave (T3 proper). R8-R12 showed schedule/
// occupancy/staging all null while LDS-read bursts and MFMA bursts serialize
// (reads-then-MFMAs in lockstep). R13 splits each K-tile into 4 phases:
//   ph p: { ds_read fragments for p ; 1 half-tile DMA of tile t+2 ;
//           barrier ; lgkmcnt(0) ; setprio(1) ; 2 MFMA ; setprio(0) }
// + one counted WAITV(4)+barrier per tile (never drains in-loop). Matrix
// pipe drains across phase boundaries while next phase's reads/stage issue.
// Geometry/offsets/ring identical to R11 (256x256xBK64, 8 waves, 3-buf ring,
// pre-swizzled DMA source, conflict-free b128 reads). MX-scaled MFMA
// (unit E8M0 = exact fp8), fp8 partials (1/16), split-K=4.
// ---------------------------------------------------------------------------

typedef float f32x4 __attribute__((ext_vector_type(4)));
typedef float f32x2 __attribute__((ext_vector_type(2)));
typedef float f32x16 __attribute__((ext_vector_type(16)));
typedef int i32x4 __attribute__((ext_vector_type(4)));
typedef int i32x8 __attribute__((ext_vector_type(8)));

#define BDIM 4096
#define DDIM 4096
#define CDIM 1024
#define TM 256
#define TN 256
#define BK 64
#define KSPLIT 4
#define NIT ((DDIM / KSPLIT) / BK)   // 16
#define SCALE 32.0f
#define INV_SS (1.0f/1024.0f)
#define PSCALE 0.0625f               // partial pack scale (1/16)

#define WAITV(N) asm volatile("s_waitcnt vmcnt(" #N ")" ::: "memory")
#define LGKM0()  asm volatile("s_waitcnt lgkmcnt(0)" ::: "memory")
#define BAR()    __builtin_amdgcn_s_barrier()

// One WAVE per row: fp32 row -> fp8(e4m3, x SCALE) row + fp32 sum-of-squares
// (of the UNSCALED values).
__global__ __launch_bounds__(256) void cvt_rowsq(
    const float* __restrict__ x, const float* __restrict__ W,
    unsigned char* __restrict__ xb, unsigned char* __restrict__ wb,
    float* __restrict__ xsq, float* __restrict__ wsq)
{
    const int lane = threadIdx.x & 63;
    const int row = blockIdx.x * 4 + (threadIdx.x >> 6);

    const float* src;
    unsigned char* dst;
    float* sq;
    if (row < BDIM) {
        src = x + (size_t)row * DDIM;
        dst = xb + (size_t)row * DDIM;
        sq = xsq + row;
    } else {
        int r = row - BDIM;
        src = W + (size_t)r * DDIM;
        dst = wb + (size_t)r * DDIM;
        sq = wsq + r;
    }

    const float4* s4 = (const float4*)src;
    unsigned int* d4 = (unsigned int*)dst;
    float a = 0.f;
    #pragma unroll
    for (int s = 0; s < DDIM / 4 / 64; ++s) {
        float4 f = s4[lane + 64 * s];
        a += f.x * f.x + f.y * f.y + f.z * f.z + f.w * f.w;
        unsigned int p = 0;
        p = __builtin_amdgcn_cvt_pk_fp8_f32(f.x * SCALE, f.y * SCALE, p, false);
        p = __builtin_amdgcn_cvt_pk_fp8_f32(f.z * SCALE, f.w * SCALE, p, true);
        d4[lane + 64 * s] = p;
    }
    #pragma unroll
    for (int off = 32; off > 0; off >>= 1) a += __shfl_down(a, off);
    if (lane == 0) *sq = a;
}

// --- GEMM ---
// LDS: 3 bufs, buf q at q*32768: A[256][64] fp8 at +0, B[256][64] at +16384.
// A half h = rows h*128 at byte h*8192 (same linear row-major layout).
// Swizzle: 16B chunk (row m, chunk c) stored at slot (m, c ^ ((m>>1)&3)).
// Staging (per phase, 1 gload/thread = 8 KB = one half): wave w covers rows
// h*128 + w*16 + (lane>>2), slot lane&3 holds global chunk
// (lane&3)^((lane>>3)&3)  [(m>>1)&3 == (lane>>3)&3 since h*64,w*8 == 0 mod 4].
// Frag reads: lane l: row base+(l&31), chunks c0=(l>>5)*2, c0^1 swizzled ->
// two ds_read_b128; 8-lane groups cover all 32 banks (conflict-free).

__device__ __forceinline__ i32x8 cat8(i32x4 lo, i32x4 hi) {
    return __builtin_shufflevector(lo, hi, 0, 1, 2, 3, 4, 5, 6, 7);
}

#define MXMFMA(A, Bv, C)                                                  \
    __builtin_amdgcn_mfma_scale_f32_32x32x64_f8f6f4(                      \
        (A), (Bv), (C), 0, 0, 0, 0x7F7F7F7F, 0, 0x7F7F7F7F)

#define GLOAD16(gp, lp)                                                   \
    __builtin_amdgcn_global_load_lds(                                     \
        (const __attribute__((address_space(1))) void*)(gp),              \
        (__attribute__((address_space(3))) void*)(lp), 16, 0, 0)

__global__ __launch_bounds__(512, 2) void gemm_eucl(
    const unsigned char* __restrict__ xb,   // [B, D] fp8
    const unsigned char* __restrict__ wb,   // [C, D] fp8
    unsigned int* __restrict__ part)        // [KSPLIT][64 blk][8 tile][4 grp][512]
{
    __shared__ unsigned char sm[3 * 32768];

    const int tid = threadIdx.x;
    const int lane = tid & 63;
    const int w = tid >> 6;                 // wave 0..7
    const int wr = w >> 2;                  // 0..1  (M half: 128 rows)
    const int wc = w & 3;                   // 0..3  (N quarter: 64 rows)
    const int bm = blockIdx.x * TM;
    const int bn = blockIdx.y * TN;
    const int ks = blockIdx.z * (DDIM / KSPLIT);

    // ---- staging: per-lane pre-swizzled global sources (coalesced) ----
    const int srow = w * 16 + (lane >> 2);          // 16 rows per wave
    const int schunk = ((lane & 3) ^ ((lane >> 3) & 3)) * 16;
    const unsigned char* gA0 = xb + (size_t)(bm + srow) * DDIM + ks + schunk;
    const unsigned char* gA1 = gA0 + (size_t)128 * DDIM;     // A half 1
    const unsigned char* gB0 = wb + (size_t)(bn + srow) * DDIM + ks + schunk;
    const unsigned char* gB1 = gB0 + (size_t)128 * DDIM;     // B half 1
    // wave-uniform LDS dests (DMA adds lane*16); one half = 8 KB
    unsigned char* lA0 = sm + w * 1024;             // A half0
    unsigned char* lA1 = lA0 + 8192;                // A half1
    unsigned char* lB0 = sm + 16384 + w * 1024;     // B half0
    unsigned char* lB1 = lB0 + 8192;                // B half1

    // ---- fragment read bases (swizzled) ----
    const int s_rd = ((lane & 31) >> 1) & 3;
    const int c0s = ((lane >> 5) * 2) ^ s_rd;
    const unsigned char* aR0 = sm + (wr * 128 + (lane & 31)) * 64 + c0s * 16;
    const unsigned char* aR1 = sm + (wr * 128 + (lane & 31)) * 64 + (c0s ^ 1) * 16;
    const unsigned char* bR0 = sm + 16384 + (wc * 64 + (lane & 31)) * 64 + c0s * 16;
    const unsigned char* bR1 = sm + 16384 + (wc * 64 + (lane & 31)) * 64 + (c0s ^ 1) * 16;

    f32x16 acc[8] = {};   // [i 0..3][j 0..1] -> acc[i*2+j]

    // ---- prologue: tiles 0,1 staged into bufs 0,1 (8 loads in flight) ----
#define STAGE_FULL(q, t)                                                  \
    do {                                                                  \
        GLOAD16(gA0 + (t) * BK, lA0 + (q) * 32768);                       \
        GLOAD16(gA1 + (t) * BK, lA1 + (q) * 32768);                       \
        GLOAD16(gB0 + (t) * BK, lB0 + (q) * 32768);                       \
        GLOAD16(gB1 + (t) * BK, lB1 + (q) * 32768);                       \
    } while (0)

    STAGE_FULL(0, 0);
    STAGE_FULL(1, 1);
    WAITV(4);            // tile 0 landed; tile 1 stays flying
    BAR();

    #pragma unroll
    for (int t = 0; t < NIT; ++t) {
        const int qo = (t % 3) * 32768;
        const int q2o = ((t + 2) % 3) * 32768;   // buf (t-1)%3: reads done @ t-1
        const bool st = (t + 2 < NIT);

        // ---------- phase 0: fb0, fb1, fa0 | stage A-half0(t+2) ----------
        i32x8 fb0 = cat8(*(const i32x4*)(bR0 + qo), *(const i32x4*)(bR1 + qo));
        i32x8 fb1 = cat8(*(const i32x4*)(bR0 + qo + 2048),
                         *(const i32x4*)(bR1 + qo + 2048));
        i32x8 fa0 = cat8(*(const i32x4*)(aR0 + qo), *(const i32x4*)(aR1 + qo));
        if (st) GLOAD16(gA0 + (t + 2) * BK, lA0 + q2o);
        BAR(); LGKM0();
        __builtin_amdgcn_s_setprio(1);
        acc[0] = MXMFMA(fa0, fb0, acc[0]);
        acc[1] = MXMFMA(fa0, fb1, acc[1]);
        __builtin_amdgcn_s_setprio(0);

        // ---------- phase 1: fa1 | stage A-half1(t+2) ----------
        i32x8 fa1 = cat8(*(const i32x4*)(aR0 + qo + 2048),
                         *(const i32x4*)(aR1 + qo + 2048));
        if (st) GLOAD16(gA1 + (t + 2) * BK, lA1 + q2o);
        BAR(); LGKM0();
        __builtin_amdgcn_s_setprio(1);
        acc[2] = MXMFMA(fa1, fb0, acc[2]);
        acc[3] = MXMFMA(fa1, fb1, acc[3]);
        __builtin_amdgcn_s_setprio(0);

        // ---------- phase 2: fa2 | stage B-half0(t+2) ----------
        i32x8 fa2 = cat8(*(const i32x4*)(aR0 + qo + 4096),
                         *(const i32x4*)(aR1 + qo + 4096));
        if (st) GLOAD16(gB0 + (t + 2) * BK, lB0 + q2o);
        BAR(); LGKM0();
        __builtin_amdgcn_s_setprio(1);
        acc[4] = MXMFMA(fa2, fb0, acc[4]);
        acc[5] = MXMFMA(fa2, fb1, acc[5]);
        __builtin_amdgcn_s_setprio(0);

        // ---------- phase 3: fa3 | stage B-half1(t+2) ----------
        i32x8 fa3 = cat8(*(const i32x4*)(aR0 + qo + 6144),
                         *(const i32x4*)(aR1 + qo + 6144));
        if (st) GLOAD16(gB1 + (t + 2) * BK, lB1 + q2o);
        BAR(); LGKM0();
        __builtin_amdgcn_s_setprio(1);
        acc[6] = MXMFMA(fa3, fb0, acc[6]);
        acc[7] = MXMFMA(fa3, fb1, acc[7]);
        __builtin_amdgcn_s_setprio(0);

        // ---------- tile boundary: counted wait, never drains in-loop ----
        if (t + 1 < NIT) {
            if (t + 2 < NIT) { WAITV(4); }   // tile t+1 landed, t+2 flying
            else             { WAITV(0); }   // t=14: drain tile 15
            BAR();
        }
    }

    // ---- fp8 partials, scale 1/16 ----
    const int bb = blockIdx.x * 4 + blockIdx.y;          // 0..63
    unsigned int* p = part + ((size_t)blockIdx.z * 64 + bb) * (32 * 512);
    #pragma unroll
    for (int f = 0; f < 8; ++f)
        #pragma unroll
        for (int g = 0; g < 4; ++g) {
            unsigned int pk = 0;
            pk = __builtin_amdgcn_cvt_pk_fp8_f32(
                acc[f][g * 4 + 0] * PSCALE, acc[f][g * 4 + 1] * PSCALE, pk, false);
            pk = __builtin_amdgcn_cvt_pk_fp8_f32(
                acc[f][g * 4 + 2] * PSCALE, acc[f][g * 4 + 3] * PSCALE, pk, true);
            p[(f * 4 + g) * 512 + tid] = pk;
        }
#undef STAGE_FULL
}

// 512 blocks x 256 thr; reduce block = one gemm-wave's 128x64 region.
// 32x32 C/D layout: col = lane&31, row = (reg&3) + 8*(reg>>2) + 4*(lane>>5);
// packed grp g holds regs 4g..4g+3 -> row = r + 8g + 4*(lane>>5).
__global__ __launch_bounds__(256) void reduce_out(
    const unsigned int* __restrict__ part, const float* __restrict__ xsq,
    const float* __restrict__ wsq, float* __restrict__ out)
{
    const int bid = blockIdx.x;           // 0..511
    const int bb = bid >> 3;              // gemm block 0..63 (bx*4 + by)
    const int w = bid & 7;                // gemm wave
    const int wr = w >> 2, wc = w & 3;
    const int t = threadIdx.x;
    const int lane = t & 63;
    const int g = t >> 6;                 // packed group 0..3
    const int bm = (bb >> 2) * TM, bn = (bb & 3) * TN;
    const size_t sl = (size_t)64 * 32 * 512;     // uints per z-slice
    const float c1 = 2.0f * 16.0f * INV_SS / (float)DDIM;  // 16 = 1/PSCALE
    const float c2 = 1.0f / (float)DDIM;

    #pragma unroll
    for (int f = 0; f < 8; ++f) {
        size_t o = ((size_t)bb * 32 + f * 4 + g) * 512 + w * 64 + lane;
        f32x2 s01 = {0.f, 0.f}, s23 = {0.f, 0.f};
        #pragma unroll
        for (int z = 0; z < KSPLIT; ++z) {
            unsigned int u = part[o + (size_t)z * sl];
            s01 += __builtin_amdgcn_cvt_pk_f32_fp8(u, false);
            s23 += __builtin_amdgcn_cvt_pk_f32_fp8(u, true);
        }
        int i = f >> 1, j = f & 1;
        int gn = bn + wc * 64 + j * 32 + (lane & 31);
        float wv = wsq[gn];
        int gm0 = bm + wr * 128 + i * 32 + 8 * g + 4 * (lane >> 5);
        float sv[4] = {s01.x, s01.y, s23.x, s23.y};
        #pragma unroll
        for (int r = 0; r < 4; ++r) {
            out[(size_t)(gm0 + r) * CDIM + gn] = sv[r] * c1 - (xsq[gm0 + r] + wv) * c2;
        }
    }
}

// --- Fallback: naive fp32 (any ws) ---
__global__ void fallback_kernel(const float* __restrict__ x, const float* __restrict__ W,
                                float* __restrict__ out)
{
    int c = blockIdx.x * blockDim.x + threadIdx.x;
    int b = blockIdx.y;
    if (c >= CDIM) return;
    const float* xr = x + (size_t)b * DDIM;
    const float* wr = W + (size_t)c * DDIM;
    float xs = 0.f, ws = 0.f, cr = 0.f;
    for (int d = 0; d < DDIM; ++d) {
        float xv = xr[d], wv = wr[d];
        xs += xv * xv; ws += wv * wv; cr += xv * wv;
    }
    out[(size_t)b * CDIM + c] = (2.0f * cr - xs - ws) / (float)DDIM;
}

extern "C" void kernel_launch(void* const* d_in, const int* in_sizes, int n_in,
                              void* d_out, int out_size, void* d_ws, size_t ws_size,
                              hipStream_t stream) {
    const float* x = (const float*)d_in[0];   // [B, D] fp32
    const float* W = (const float*)d_in[1];   // [C, D] fp32
    float* out = (float*)d_out;               // [B, C] fp32

    size_t need = (size_t)(BDIM + CDIM) * DDIM                 // fp8 inputs 20 MB
                + (size_t)(BDIM + CDIM) * sizeof(float)        // norms
                + (size_t)KSPLIT * BDIM * CDIM;                // fp8 partials 16 MB
    if (ws_size < need) {
        fallback_kernel<<<dim3(CDIM / 256, BDIM), 256, 0, stream>>>(x, W, out);
        return;
    }

    unsigned char* xb = (unsigned char*)d_ws;              // 16 MB
    unsigned char* wb = xb + (size_t)BDIM * DDIM;          // 4 MB
    float* xsq = (float*)(wb + (size_t)CDIM * DDIM);       // 16 KB
    float* wsq = xsq + BDIM;                               // 4 KB
    unsigned int* part = (unsigned int*)(wsq + CDIM);      // 16 MB

    cvt_rowsq<<<(BDIM + CDIM) / 4, 256, 0, stream>>>(x, W, xb, wb, xsq, wsq);
    gemm_eucl<<<dim3(BDIM / TM, CDIM / TN, KSPLIT), 512, 0, stream>>>(xb, wb, part);
    reduce_out<<<512, 256, 0, stream>>>(part, xsq, wsq, out);
}

// Round 8
// 132.621 us; speedup vs baseline: 1.0538x; 1.0156x over previous
//
#include <hip/hip_runtime.h>
#include <hip/hip_bf16.h>

// ---------------------------------------------------------------------------
// EuclideanDeconf: out[b,c] = (2*dot(x[b],W[c]) - ||x[b]||^2 - ||W[c]||^2) / D
// R14: pipeline fusion. Five K-loop structures (R8..R13) all pinned the gemm
// at 30-35us (MX MFMA in-context != 2x ubench rate; stall/MFMA invariant to
// schedule AND occupancy). So stop rescheduling; delete the split-K partial
// round-trip instead: KSPLIT=1, NIT=64, epilogue fused into the gemm
// (out = acc*2/(1024*D) - (xsq+wsq)/D), reduce_out kernel deleted, 16.7 MB
// partial write + 16.7 MB cross-XCD read-back eliminated.
// K-loop = R12's verified machinery, ring-of-4 LDS bufs (64 KB), PD=2-tile
// flight, counted WAITV(4) (never drains until the 2 peeled tail iters),
// pre-swizzled DMA source + swizzled conflict-free b128 reads (rule #21).
// 128x128xBK64, 256 thr (4 waves 2x2, wave=64x64), grid (32,8)=256.
// ---------------------------------------------------------------------------

typedef float f32x4 __attribute__((ext_vector_type(4)));
typedef float f32x2 __attribute__((ext_vector_type(2)));
typedef float f32x16 __attribute__((ext_vector_type(16)));
typedef int i32x4 __attribute__((ext_vector_type(4)));
typedef int i32x8 __attribute__((ext_vector_type(8)));

#define BDIM 4096
#define DDIM 4096
#define CDIM 1024
#define TM 128
#define TN 128
#define BK 64
#define NIT (DDIM / BK)              // 64
#define SCALE 32.0f
#define INV_SS (1.0f/1024.0f)

#define WAITV(N) asm volatile("s_waitcnt vmcnt(" #N ")" ::: "memory")
#define BAR()    __builtin_amdgcn_s_barrier()

// One WAVE per row: fp32 row -> fp8(e4m3, x SCALE) row + fp32 sum-of-squares
// (of the UNSCALED values).
__global__ __launch_bounds__(256) void cvt_rowsq(
    const float* __restrict__ x, const float* __restrict__ W,
    unsigned char* __restrict__ xb, unsigned char* __restrict__ wb,
    float* __restrict__ xsq, float* __restrict__ wsq)
{
    const int lane = threadIdx.x & 63;
    const int row = blockIdx.x * 4 + (threadIdx.x >> 6);

    const float* src;
    unsigned char* dst;
    float* sq;
    if (row < BDIM) {
        src = x + (size_t)row * DDIM;
        dst = xb + (size_t)row * DDIM;
        sq = xsq + row;
    } else {
        int r = row - BDIM;
        src = W + (size_t)r * DDIM;
        dst = wb + (size_t)r * DDIM;
        sq = wsq + r;
    }

    const float4* s4 = (const float4*)src;
    unsigned int* d4 = (unsigned int*)dst;
    float a = 0.f;
    #pragma unroll
    for (int s = 0; s < DDIM / 4 / 64; ++s) {
        float4 f = s4[lane + 64 * s];
        a += f.x * f.x + f.y * f.y + f.z * f.z + f.w * f.w;
        unsigned int p = 0;
        p = __builtin_amdgcn_cvt_pk_fp8_f32(f.x * SCALE, f.y * SCALE, p, false);
        p = __builtin_amdgcn_cvt_pk_fp8_f32(f.z * SCALE, f.w * SCALE, p, true);
        d4[lane + 64 * s] = p;
    }
    #pragma unroll
    for (int off = 32; off > 0; off >>= 1) a += __shfl_down(a, off);
    if (lane == 0) *sq = a;
}

// --- GEMM + fused epilogue ---
// LDS: 4 bufs, buf q at q*16384: A[128][64] fp8 at +0, B[128][64] at +8192.
// Swizzle: 16B chunk (row m, chunk c) stored at slot (m, c ^ ((m>>1)&3)).
// Staging (verified R12): wave w rows w*32+(lane>>2) (+16 for 2nd inst),
// slot lane&3 holds global chunk (lane&3)^((lane>>3)&3); DMA writes linearly
// (base + lane*16); per-lane SOURCE pre-swizzled, same 64B line per 4-lane
// group -> fully coalesced.
// Frag reads (verified R12): lane l: row base+(l&31), chunks c0=(l>>5)*2 and
// c0^1 swizzled -> two ds_read_b128; 8-lane groups cover all 32 banks.

__device__ __forceinline__ i32x8 cat8(i32x4 lo, i32x4 hi) {
    return __builtin_shufflevector(lo, hi, 0, 1, 2, 3, 4, 5, 6, 7);
}

#define MXMFMA(A, Bv, C)                                                  \
    __builtin_amdgcn_mfma_scale_f32_32x32x64_f8f6f4(                      \
        (A), (Bv), (C), 0, 0, 0, 0x7F7F7F7F, 0, 0x7F7F7F7F)

#define GLOAD16(gp, lp)                                                   \
    __builtin_amdgcn_global_load_lds(                                     \
        (const __attribute__((address_space(1))) void*)(gp),              \
        (__attribute__((address_space(3))) void*)(lp), 16, 0, 0)

__global__ __launch_bounds__(256) void gemm_eucl(
    const unsigned char* __restrict__ xb,   // [B, D] fp8
    const unsigned char* __restrict__ wb,   // [C, D] fp8
    const float* __restrict__ xsq, const float* __restrict__ wsq,
    float* __restrict__ out)                // [B, C] fp32
{
    __shared__ unsigned char sm[4 * 16384];

    const int tid = threadIdx.x;
    const int lane = tid & 63;
    const int w = tid >> 6;                 // wave 0..3
    const int wr = w >> 1;                  // 0..1  (M half: 64 rows)
    const int wc = w & 1;                   // 0..1  (N half: 64 rows)
    const int bm = blockIdx.x * TM;
    const int bn = blockIdx.y * TN;

    // ---- staging: per-lane pre-swizzled global sources (coalesced) ----
    const int srow = w * 32 + (lane >> 2);
    const int schunk = ((lane & 3) ^ ((lane >> 3) & 3)) * 16;
    const unsigned char* gA0 = xb + (size_t)(bm + srow) * DDIM + schunk;
    const unsigned char* gA1 = gA0 + (size_t)16 * DDIM;
    const unsigned char* gB0 = wb + (size_t)(bn + srow) * DDIM + schunk;
    const unsigned char* gB1 = gB0 + (size_t)16 * DDIM;
    // wave-uniform LDS dests (DMA adds lane*16)
    unsigned char* lA0 = sm + w * 2048;
    unsigned char* lA1 = lA0 + 1024;
    unsigned char* lB0 = sm + 8192 + w * 2048;
    unsigned char* lB1 = lB0 + 1024;

#define STAGE(q, t)                                                       \
    do {                                                                  \
        GLOAD16(gA0 + (t) * BK, lA0 + (q) * 16384);                       \
        GLOAD16(gA1 + (t) * BK, lA1 + (q) * 16384);                       \
        GLOAD16(gB0 + (t) * BK, lB0 + (q) * 16384);                       \
        GLOAD16(gB1 + (t) * BK, lB1 + (q) * 16384);                       \
    } while (0)

    // ---- fragment read bases (swizzled) ----
    const int s_rd = ((lane & 31) >> 1) & 3;
    const int c0s = ((lane >> 5) * 2) ^ s_rd;
    const unsigned char* aR0 = sm + (wr * 64 + (lane & 31)) * 64 + c0s * 16;
    const unsigned char* aR1 = sm + (wr * 64 + (lane & 31)) * 64 + (c0s ^ 1) * 16;
    const unsigned char* bR0 = sm + 8192 + (wc * 64 + (lane & 31)) * 64 + c0s * 16;
    const unsigned char* bR1 = sm + 8192 + (wc * 64 + (lane & 31)) * 64 + (c0s ^ 1) * 16;

    f32x16 acc[4] = {};   // [i 0..1][j 0..1] -> acc[i*2+j]

#define COMPUTE(qo)                                                       \
    do {                                                                  \
        i32x8 fb0 = cat8(*(const i32x4*)(bR0 + (qo)),                     \
                         *(const i32x4*)(bR1 + (qo)));                    \
        i32x8 fb1 = cat8(*(const i32x4*)(bR0 + (qo) + 2048),              \
                         *(const i32x4*)(bR1 + (qo) + 2048));             \
        i32x8 fa0 = cat8(*(const i32x4*)(aR0 + (qo)),                     \
                         *(const i32x4*)(aR1 + (qo)));                    \
        i32x8 fa1 = cat8(*(const i32x4*)(aR0 + (qo) + 2048),              \
                         *(const i32x4*)(aR1 + (qo) + 2048));             \
        __builtin_amdgcn_s_setprio(1);                                    \
        acc[0] = MXMFMA(fa0, fb0, acc[0]);                                \
        acc[1] = MXMFMA(fa0, fb1, acc[1]);                                \
        acc[2] = MXMFMA(fa1, fb0, acc[2]);                                \
        acc[3] = MXMFMA(fa1, fb1, acc[3]);                                \
        __builtin_amdgcn_s_setprio(0);                                    \
    } while (0)

    // ---- prologue: tiles 0,1 staged into bufs 0,1 (8 loads in flight) ----
    STAGE(0, 0);
    STAGE(1, 1);

    // main loop: stages t+2; WAITV(4) retires tile t, keeps t+1 flying
    #pragma unroll 4
    for (int t = 0; t < NIT - 2; ++t) {
        WAITV(4);
        BAR();
        STAGE((t + 2) & 3, t + 2);   // buf (t-2)&3: reads done at t-2
        COMPUTE((t & 3) * 16384);
    }
    // peeled tail (no staging)
    WAITV(4); BAR(); COMPUTE(((NIT - 2) & 3) * 16384);
    WAITV(0); BAR(); COMPUTE(((NIT - 1) & 3) * 16384);

    // ---- fused epilogue ----
    // 32x32 C/D layout: col = lane&31, row = (reg&3)+8*(reg>>2)+4*(lane>>5).
    const float c1m = 2.0f * INV_SS / (float)DDIM;
    const float c2 = 1.0f / (float)DDIM;
    const int gn0 = bn + wc * 64 + (lane & 31);
    const int gm_b = bm + wr * 64 + (lane >> 5) * 4;
    const float wv0 = wsq[gn0];
    const float wv1 = wsq[gn0 + 32];
    #pragma unroll
    for (int i = 0; i < 2; ++i)
        #pragma unroll
        for (int g = 0; g < 4; ++g)
            #pragma unroll
            for (int r = 0; r < 4; ++r) {
                const int gm = gm_b + i * 32 + g * 8 + r;
                const float xs = xsq[gm];
                out[(size_t)gm * CDIM + gn0] =
                    acc[i * 2 + 0][g * 4 + r] * c1m - (xs + wv0) * c2;
                out[(size_t)gm * CDIM + gn0 + 32] =
                    acc[i * 2 + 1][g * 4 + r] * c1m - (xs + wv1) * c2;
            }
#undef STAGE
#undef COMPUTE
}

// --- Fallback: naive fp32 (any ws) ---
__global__ void fallback_kernel(const float* __restrict__ x, const float* __restrict__ W,
                                float* __restrict__ out)
{
    int c = blockIdx.x * blockDim.x + threadIdx.x;
    int b = blockIdx.y;
    if (c >= CDIM) return;
    const float* xr = x + (size_t)b * DDIM;
    const float* wr = W + (size_t)c * DDIM;
    float xs = 0.f, ws = 0.f, cr = 0.f;
    for (int d = 0; d < DDIM; ++d) {
        float xv = xr[d], wv = wr[d];
        xs += xv * xv; ws += wv * wv; cr += xv * wv;
    }
    out[(size_t)b * CDIM + c] = (2.0f * cr - xs - ws) / (float)DDIM;
}

extern "C" void kernel_launch(void* const* d_in, const int* in_sizes, int n_in,
                              void* d_out, int out_size, void* d_ws, size_t ws_size,
                              hipStream_t stream) {
    const float* x = (const float*)d_in[0];   // [B, D] fp32
    const float* W = (const float*)d_in[1];   // [C, D] fp32
    float* out = (float*)d_out;               // [B, C] fp32

    size_t need = (size_t)(BDIM + CDIM) * DDIM                 // fp8 inputs 20 MB
                + (size_t)(BDIM + CDIM) * sizeof(float);       // norms
    if (ws_size < need) {
        fallback_kernel<<<dim3(CDIM / 256, BDIM), 256, 0, stream>>>(x, W, out);
        return;
    }

    unsigned char* xb = (unsigned char*)d_ws;              // 16 MB
    unsigned char* wb = xb + (size_t)BDIM * DDIM;          // 4 MB
    float* xsq = (float*)(wb + (size_t)CDIM * DDIM);       // 16 KB
    float* wsq = xsq + BDIM;                               // 4 KB

    cvt_rowsq<<<(BDIM + CDIM) / 4, 256, 0, stream>>>(x, W, xb, wb, xsq, wsq);
    gemm_eucl<<<dim3(BDIM / TM, CDIM / TN), 256, 0, stream>>>(xb, wb, xsq, wsq, out);
}